// Round 5
// baseline (236.654 us; speedup 1.0000x reference)
//
#include <hip/hip_runtime.h>
#include <hip/hip_bf16.h>

#define EMBED 256
#define NH 8
#define NL 4
#define NP 4
#define HD 32
#define BS 4
#define NQ 4000
#define NV 13294

using f32x4   = __attribute__((ext_vector_type(4))) float;
using bf16x8  = __attribute__((ext_vector_type(8))) short;

__device__ __forceinline__ float bf2f_lo(unsigned u) {
    union { unsigned u; float f; } x; x.u = u << 16; return x.f;
}
__device__ __forceinline__ float bf2f_hi(unsigned u) {
    union { unsigned u; float f; } x; x.u = u & 0xffff0000u; return x.f;
}
__device__ __forceinline__ unsigned short f2bf(float f) {
    union { float f; unsigned u; } x; x.f = f;
    unsigned u = x.u;
    return (unsigned short)((u + 0x7fffu + ((u >> 16) & 1u)) >> 16);
}

// async 16B/lane global->LDS DMA (global_load_lds_dwordx4)
__device__ __forceinline__ void async16(const void* g, void* l) {
    __builtin_amdgcn_global_load_lds(
        (const __attribute__((address_space(1))) void*)g,
        (__attribute__((address_space(3))) void*)l, 16, 0, 0);
}

// ---------- fp32 -> bf16 bulk convert (4 elems/thread) ----------
__global__ __launch_bounds__(256) void msda_cvt_k(const float* __restrict__ in,
                                                  unsigned short* __restrict__ out, int n4) {
    int i = blockIdx.x * 256 + threadIdx.x;
    if (i < n4) {
        float4 v = ((const float4*)in)[i];
        unsigned lo = f2bf(v.x) | ((unsigned)f2bf(v.y) << 16);
        unsigned hi = f2bf(v.z) | ((unsigned)f2bf(v.w) << 16);
        uint2 o = {lo, hi};
        ((uint2*)out)[i] = o;
    }
}

// ---------- prep: fused weight transposes + bias concat ----------
__global__ void msda_prep_k(const float* __restrict__ W_val, const float* __restrict__ W_out,
                            const float* __restrict__ W_off, const float* __restrict__ W_attn,
                            const float* __restrict__ b_off, const float* __restrict__ b_attn,
                            unsigned short* __restrict__ Wt_val, unsigned short* __restrict__ Wt_out,
                            unsigned short* __restrict__ Wt_qa, float* __restrict__ b_qa) {
    int i = blockIdx.x * 256 + threadIdx.x;
    if (i < 384) b_qa[i] = (i < 256) ? b_off[i] : b_attn[i - 256];
    if (i < 65536) {
        int r = i >> 8, c = i & 255;
        Wt_val[c * 256 + r] = f2bf(W_val[i]);
    } else if (i < 131072) {
        int j = i - 65536, r = j >> 8, c = j & 255;
        Wt_out[c * 256 + r] = f2bf(W_out[j]);
    } else if (i < 229376) {
        int j = i - 131072;           // j = n*256 + k, n in [0,384)
        int n = j >> 8, k = j & 255;
        float v = (n < 256) ? W_off[k * 256 + n] : W_attn[k * 128 + (n - 256)];
        Wt_qa[j] = f2bf(v);
    }
}

// ---------- GEMM: 128x128 tile, global_load_lds staging, 4x4 MFMA/wave ----------
// A bf16 [M][K], Bt = B^T bf16 [N][K], bias fp32 [N].
// EPI 0: bf16 store to v layout [b][h][s][d];  EPI 1: fp32 row-major [M][N].
template<int EPI>
__global__ __launch_bounds__(256) void msda_gemm_k(
    const unsigned short* __restrict__ A,
    const unsigned short* __restrict__ Bt,
    const float* __restrict__ bias,
    void* __restrict__ out,
    int M, int N, int K)
{
    __shared__ __align__(16) unsigned short As[128][32];
    __shared__ __align__(16) unsigned short Bs[128][32];
    const int m0 = blockIdx.x * 128, n0 = blockIdx.y * 128;
    const int tid  = threadIdx.x;
    const int w    = tid >> 6;
    const int lane = tid & 63;
    const int quad = lane >> 4;
    const int l16  = lane & 15;
    const int wm   = w & 1, wn = w >> 1;

    // staging: wave w DMAs segments 2w, 2w+1 (16 rows x 64 B each) of As and Bs
    const int rseg = lane >> 2;          // row within segment
    const int cb   = (lane & 3) * 16;    // byte col within 64-B row chunk
    const int s0 = 2 * w, s1 = s0 + 1;
    const int am0 = min(m0 + s0 * 16 + rseg, M - 1);
    const int am1 = min(m0 + s1 * 16 + rseg, M - 1);
    const char* agp0 = (const char*)(A  + (size_t)am0 * K) + cb;
    const char* agp1 = (const char*)(A  + (size_t)am1 * K) + cb;
    const char* bgp0 = (const char*)(Bt + (size_t)(n0 + s0 * 16 + rseg) * K) + cb;
    const char* bgp1 = (const char*)(Bt + (size_t)(n0 + s1 * 16 + rseg) * K) + cb;
    char* lA0 = (char*)&As[0][0] + s0 * 1024;
    char* lA1 = (char*)&As[0][0] + s1 * 1024;
    char* lB0 = (char*)&Bs[0][0] + s0 * 1024;
    char* lB1 = (char*)&Bs[0][0] + s1 * 1024;

    f32x4 acc[4][4];
#pragma unroll
    for (int a = 0; a < 4; a++)
#pragma unroll
        for (int b = 0; b < 4; b++) acc[a][b] = (f32x4){0.f, 0.f, 0.f, 0.f};

    for (int k0 = 0; k0 < K; k0 += 32) {
        const int kb = k0 * 2;
        async16(agp0 + kb, lA0);
        async16(agp1 + kb, lA1);
        async16(bgp0 + kb, lB0);
        async16(bgp1 + kb, lB1);
        __syncthreads();

        bf16x8 af[4], bfr[4];
#pragma unroll
        for (int mi = 0; mi < 4; mi++) af[mi]  = *(const bf16x8*)&As[wm * 64 + mi * 16 + l16][quad * 8];
#pragma unroll
        for (int ni = 0; ni < 4; ni++) bfr[ni] = *(const bf16x8*)&Bs[wn * 64 + ni * 16 + l16][quad * 8];
#pragma unroll
        for (int mi = 0; mi < 4; mi++)
#pragma unroll
            for (int ni = 0; ni < 4; ni++)
                acc[mi][ni] = __builtin_amdgcn_mfma_f32_16x16x32_bf16(af[mi], bfr[ni], acc[mi][ni], 0, 0, 0);
        __syncthreads();
    }

#pragma unroll
    for (int ni = 0; ni < 4; ni++) {
        int c = n0 + wn * 64 + ni * 16 + l16;
        float bvv = bias[c];
#pragma unroll
        for (int mi = 0; mi < 4; mi++) {
#pragma unroll
            for (int r = 0; r < 4; r++) {
                int m = m0 + wm * 64 + mi * 16 + quad * 4 + r;
                if (m >= M) continue;
                float val = acc[mi][ni][r] + bvv;
                if (EPI == 0) {
                    int b = m / NV, s = m % NV;
                    int h = c >> 5, d = c & 31;
                    ((unsigned short*)out)[(((size_t)(b * NH + h) * NV + s) << 5) + d] = f2bf(val);
                } else {
                    ((float*)out)[(size_t)m * N + c] = val;
                }
            }
        }
    }
}

// ---------- sampler: 4 queries/block, wave = 1 query, thread = (h, 4-chan grp) ----------
__global__ __launch_bounds__(256) void msda_sampler_k(
    const float* __restrict__ refpts,            // (BS*NQ, 8) fp32
    const float* __restrict__ oa_buf,            // (BS*NQ, 384) fp32: off[256] | attn[128]
    const unsigned short* __restrict__ v_buf,    // (BS,NH,NV,HD) bf16
    unsigned short* __restrict__ t_out)          // (BS*NQ, 256) bf16
{
    __shared__ float  oa_s[4][384];
    __shared__ float  ref_s[4][8];
    __shared__ float4 wtab[512];                 // [lp][ql][h]
    __shared__ int4   itab[512];

    const int tid = threadIdx.x;
    const int q0  = blockIdx.x * 4;

    {
        const float4* src = (const float4*)(oa_buf + (size_t)q0 * 384);
        float4* dst = (float4*)&oa_s[0][0];
        dst[tid] = src[tid];
        if (tid < 128) dst[256 + tid] = src[256 + tid];
        if (tid < 32) ((float*)ref_s)[tid] = refpts[q0 * 8 + tid];
    }
    __syncthreads();

    if (tid < 32) {  // softmax over 16 per (q,h)
        float* lg = &oa_s[tid >> 3][256 + (tid & 7) * 16];
        float mx = -1e30f;
#pragma unroll
        for (int i = 0; i < 16; i++) mx = fmaxf(mx, lg[i]);
        float s = 0.f;
#pragma unroll
        for (int i = 0; i < 16; i++) { float e = __expf(lg[i] - mx); lg[i] = e; s += e; }
        float inv = 1.f / s;
#pragma unroll
        for (int i = 0; i < 16; i++) lg[i] *= inv;
    }
    __syncthreads();

    const int HWs[4]    = {100, 50, 25, 13};
    const int starts[4] = {0, 10000, 12500, 13125};
#pragma unroll
    for (int pt = tid; pt < 512; pt += 256) {
        int ql = pt >> 7, pid = pt & 127;
        int h = pid >> 4, l = (pid >> 2) & 3, p = pid & 3;
        int Wl = HWs[l];
        float fW = (float)Wl;
        float rx = ref_s[ql][l * 2], ry = ref_s[ql][l * 2 + 1];
        float offx = oa_s[ql][(h * 32) + l * 8 + p * 2];
        float offy = oa_s[ql][(h * 32) + l * 8 + p * 2 + 1];
        float a = oa_s[ql][256 + pid];
        float x = rx * fW + offx - 0.5f;
        float y = ry * fW + offy - 0.5f;
        float xf = floorf(x), yf = floorf(y);
        float fx = x - xf, fy = y - yf;
        int x0 = (int)xf, y0 = (int)yf;
        int x1 = x0 + 1, y1 = y0 + 1;
        float wx0 = (x0 >= 0 && x0 < Wl) ? (1.f - fx) : 0.f;
        float wx1 = (x1 >= 0 && x1 < Wl) ? fx : 0.f;
        float wy0 = (y0 >= 0 && y0 < Wl) ? (1.f - fy) : 0.f;
        float wy1 = (y1 >= 0 && y1 < Wl) ? fy : 0.f;
        int x0c = min(max(x0, 0), Wl - 1), x1c = min(max(x1, 0), Wl - 1);
        int y0c = min(max(y0, 0), Wl - 1), y1c = min(max(y1, 0), Wl - 1);
        int r0 = starts[l] + y0c * Wl, r1 = starts[l] + y1c * Wl;
        int ti = ((pid & 15) << 5) | (ql << 3) | h;
        wtab[ti] = make_float4(wx0 * wy0 * a, wx1 * wy0 * a, wx0 * wy1 * a, wx1 * wy1 * a);
        itab[ti] = make_int4(r0 + x0c, r0 + x1c, r1 + x0c, r1 + x1c);
    }
    __syncthreads();

    const int dg = tid & 7, h = (tid >> 3) & 7, ql = tid >> 6;
    const int q = q0 + ql;
    const int b = q / NQ;
    const unsigned short* vb = v_buf + ((size_t)(b * NH + h) * NV) * HD + dg * 4;
    const int tbase = (ql << 3) | h;

    float a0 = 0.f, a1 = 0.f, a2 = 0.f, a3 = 0.f;
#pragma unroll
    for (int lp = 0; lp < 16; lp++) {
        float4 wv = wtab[(lp << 5) | tbase];
        int4   ix = itab[(lp << 5) | tbase];
        uint2 s0 = *(const uint2*)(vb + (size_t)ix.x * HD);
        uint2 s1 = *(const uint2*)(vb + (size_t)ix.y * HD);
        uint2 s2 = *(const uint2*)(vb + (size_t)ix.z * HD);
        uint2 s3 = *(const uint2*)(vb + (size_t)ix.w * HD);
        a0 += wv.x * bf2f_lo(s0.x); a1 += wv.x * bf2f_hi(s0.x);
        a2 += wv.x * bf2f_lo(s0.y); a3 += wv.x * bf2f_hi(s0.y);
        a0 += wv.y * bf2f_lo(s1.x); a1 += wv.y * bf2f_hi(s1.x);
        a2 += wv.y * bf2f_lo(s1.y); a3 += wv.y * bf2f_hi(s1.y);
        a0 += wv.z * bf2f_lo(s2.x); a1 += wv.z * bf2f_hi(s2.x);
        a2 += wv.z * bf2f_lo(s2.y); a3 += wv.z * bf2f_hi(s2.y);
        a0 += wv.w * bf2f_lo(s3.x); a1 += wv.w * bf2f_hi(s3.x);
        a2 += wv.w * bf2f_lo(s3.y); a3 += wv.w * bf2f_hi(s3.y);
    }
    unsigned o0 = (unsigned)f2bf(a0) | ((unsigned)f2bf(a1) << 16);
    unsigned o1 = (unsigned)f2bf(a2) | ((unsigned)f2bf(a3) << 16);
    uint2 o = {o0, o1};
    *(uint2*)(t_out + (size_t)q * 256 + h * 32 + dg * 4) = o;
}

extern "C" void kernel_launch(void* const* d_in, const int* in_sizes, int n_in,
                              void* d_out, int out_size, void* d_ws, size_t ws_size,
                              hipStream_t stream) {
    const float* query  = (const float*)d_in[0];
    const float* value  = (const float*)d_in[1];
    const float* refpts = (const float*)d_in[2];
    // d_in[3] = spatial_shapes (int32) — fixed {100,50,25,13}^2, hard-coded.
    const float* W_off  = (const float*)d_in[4];
    const float* b_off  = (const float*)d_in[5];
    const float* W_attn = (const float*)d_in[6];
    const float* b_attn = (const float*)d_in[7];
    const float* W_val  = (const float*)d_in[8];
    const float* b_val  = (const float*)d_in[9];
    const float* W_out  = (const float*)d_in[10];
    const float* b_out  = (const float*)d_in[11];

    char* wsp = (char*)d_ws;
    size_t o = 0;
    auto carve = [&](size_t bytes) -> void* {
        void* p = wsp + o; o += (bytes + 255) & ~(size_t)255; return p;
    };
    unsigned short* Wt_val = (unsigned short*)carve(256 * 256 * 2);
    unsigned short* Wt_out = (unsigned short*)carve(256 * 256 * 2);
    unsigned short* Wt_qa  = (unsigned short*)carve(384 * 256 * 2);
    float*          b_qa   = (float*)carve(384 * 4);
    unsigned short* v_buf  = (unsigned short*)carve((size_t)BS * NH * NV * HD * 2);
    // region X: value_bf (27.23 MB), later reused as oa_buf (24.58 MB)
    char* regX = (char*)carve((size_t)BS * NV * EMBED * 2);
    unsigned short* value_bf = (unsigned short*)regX;
    float*          oa_buf   = (float*)regX;
    // region Y: query_bf (8.19 MB), later reused as t_buf (8.19 MB)
    char* regY = (char*)carve((size_t)BS * NQ * EMBED * 2);
    unsigned short* query_bf = (unsigned short*)regY;
    unsigned short* t_buf    = (unsigned short*)regY;
    // total ~63.2 MB

    msda_prep_k<<<896, 256, 0, stream>>>(W_val, W_out, W_off, W_attn, b_off, b_attn,
                                         Wt_val, Wt_out, Wt_qa, b_qa);
    msda_cvt_k<<<(BS * NV * EMBED / 4 + 255) / 256, 256, 0, stream>>>(value, value_bf, BS * NV * EMBED / 4);
    msda_cvt_k<<<(BS * NQ * EMBED / 4) / 256, 256, 0, stream>>>(query, query_bf, BS * NQ * EMBED / 4);

    const int Mv = BS * NV;   // 53176
    const int Mq = BS * NQ;   // 16000
    msda_gemm_k<0><<<dim3((Mv + 127) / 128, 2), 256, 0, stream>>>(value_bf, Wt_val, b_val, v_buf, Mv, 256, 256);
    // qa-GEMM reads query_bf (regY) and writes oa_buf (regX) — value_bf already consumed.
    msda_gemm_k<1><<<dim3(Mq / 128, 3), 256, 0, stream>>>(query_bf, Wt_qa, b_qa, oa_buf, Mq, 384, 256);
    // sampler reads oa_buf (regX), writes t_buf (regY) — query_bf already consumed.
    msda_sampler_k<<<Mq / 4, 256, 0, stream>>>(refpts, oa_buf, v_buf, t_buf);
    msda_gemm_k<1><<<dim3(Mq / 128, 2), 256, 0, stream>>>(t_buf, Wt_out, b_out, (float*)d_out, Mq, 256, 256);
}

// Round 7
// 218.406 us; speedup vs baseline: 1.0835x; 1.0835x over previous
//
#include <hip/hip_runtime.h>
#include <hip/hip_bf16.h>

#define EMBED 256
#define NH 8
#define NL 4
#define NP 4
#define HD 32
#define BS 4
#define NQ 4000
#define NV 13294

using f32x4   = __attribute__((ext_vector_type(4))) float;
using bf16x8  = __attribute__((ext_vector_type(8))) short;

__device__ __forceinline__ float bf2f_lo(unsigned u) {
    union { unsigned u; float f; } x; x.u = u << 16; return x.f;
}
__device__ __forceinline__ float bf2f_hi(unsigned u) {
    union { unsigned u; float f; } x; x.u = u & 0xffff0000u; return x.f;
}
__device__ __forceinline__ unsigned short f2bf(float f) {
    union { float f; unsigned u; } x; x.f = f;
    unsigned u = x.u;
    return (unsigned short)((u + 0x7fffu + ((u >> 16) & 1u)) >> 16);
}

// async 16B/lane global->LDS DMA (global_load_lds_dwordx4).
// LDS dest is wave-uniform base; lane i lands at base + i*16.
__device__ __forceinline__ void async16(const void* g, void* l) {
    __builtin_amdgcn_global_load_lds(
        (const __attribute__((address_space(1))) void*)g,
        (__attribute__((address_space(3))) void*)l, 16, 0, 0);
}

// ---------- fused prep: value/query fp32->bf16 + weight transposes ----------
__global__ __launch_bounds__(256) void msda_prep_k(
    const float* __restrict__ value, const float* __restrict__ query,
    const float* __restrict__ W_val, const float* __restrict__ W_out,
    const float* __restrict__ W_off, const float* __restrict__ W_attn,
    const float* __restrict__ b_off, const float* __restrict__ b_attn,
    unsigned short* __restrict__ value_bf, unsigned short* __restrict__ query_bf,
    unsigned short* __restrict__ Wt_val, unsigned short* __restrict__ Wt_out,
    unsigned short* __restrict__ Wt_qa, float* __restrict__ b_qa)
{
    const int bid = blockIdx.x, tid = threadIdx.x;
    if (bid < 13294) {                       // value cvt: 3,403,264 uint2 elems
        int i = bid * 256 + tid;
        float4 v = ((const float4*)value)[i];
        uint2 o = { f2bf(v.x) | ((unsigned)f2bf(v.y) << 16),
                    f2bf(v.z) | ((unsigned)f2bf(v.w) << 16) };
        ((uint2*)value_bf)[i] = o;
    } else if (bid < 17294) {                // query cvt: 1,024,000 uint2 elems
        int i = (bid - 13294) * 256 + tid;
        float4 v = ((const float4*)query)[i];
        uint2 o = { f2bf(v.x) | ((unsigned)f2bf(v.y) << 16),
                    f2bf(v.z) | ((unsigned)f2bf(v.w) << 16) };
        ((uint2*)query_bf)[i] = o;
    } else {                                 // weights: 229,376 elems over 896 blocks
        int i = (bid - 17294) * 256 + tid;
        if (i < 384) b_qa[i] = (i < 256) ? b_off[i] : b_attn[i - 256];
        if (i < 65536) {
            int r = i >> 8, c = i & 255;
            Wt_val[c * 256 + r] = f2bf(W_val[i]);
        } else if (i < 131072) {
            int j = i - 65536, r = j >> 8, c = j & 255;
            Wt_out[c * 256 + r] = f2bf(W_out[j]);
        } else if (i < 229376) {
            int j = i - 131072;              // j = n*256 + k, n in [0,384)
            int n = j >> 8, k = j & 255;
            float v = (n < 256) ? W_off[k * 256 + n] : W_attn[k * 128 + (n - 256)];
            Wt_qa[j] = f2bf(v);
        }
    }
}

// ---------- GEMM: TM x 128 tile, double-buffered global_load_lds prefetch ----------
// A bf16 [M][K], Bt = B^T bf16 [N][K], bias fp32 [N].
// EPI 0: bf16 row-major [M][N];  EPI 1: fp32 row-major [M][N].
template<int TM, int EPI>
__global__ __launch_bounds__(256) void msda_gemm_k(
    const unsigned short* __restrict__ A,
    const unsigned short* __restrict__ Bt,
    const float* __restrict__ bias,
    void* __restrict__ out,
    int M, int N, int K)
{
    constexpr int NI = (TM == 128) ? 4 : 2;
    __shared__ __align__(16) unsigned short As[2][TM][32];
    __shared__ __align__(16) unsigned short Bs[2][128][32];
    const int m0 = blockIdx.x * TM, n0 = blockIdx.y * 128;
    const int tid  = threadIdx.x;
    const int w    = tid >> 6;
    const int lane = tid & 63;
    const int quad = lane >> 4;
    const int l16  = lane & 15;
    const int wm   = (TM == 128) ? (w & 1) * 64 : 0;
    const int wn   = (TM == 128) ? (w >> 1) * 64 : w * 32;

    // staging geometry: segment = 16 rows x 64 B; lane -> (row lane>>2, 16B chunk lane&3)
    const int rseg = lane >> 2;
    const int cb   = (lane & 3) * 16;

    int ar0, ar1 = 0;
    if (TM == 128) {
        ar0 = min(m0 + (2 * w) * 16 + rseg, M - 1);
        ar1 = min(m0 + (2 * w + 1) * 16 + rseg, M - 1);
    } else {
        ar0 = min(m0 + w * 16 + rseg, M - 1);
    }
    const char* agp0 = (const char*)(A + (size_t)ar0 * K) + cb;
    const char* agp1 = (TM == 128) ? (const char*)(A + (size_t)ar1 * K) + cb : agp0;
    const char* bgp0 = (const char*)(Bt + (size_t)(n0 + (2 * w) * 16 + rseg) * K) + cb;
    const char* bgp1 = (const char*)(Bt + (size_t)(n0 + (2 * w + 1) * 16 + rseg) * K) + cb;

    auto issue = [&](int chunk, int buf) {
        const int kb = chunk * 64;   // chunk * 32 elements * 2 B  (R6 bug: was chunk*2)
        char* a = (char*)&As[buf][0][0];
        char* b = (char*)&Bs[buf][0][0];
        if (TM == 128) {
            async16(agp0 + kb, a + (2 * w) * 1024);
            async16(agp1 + kb, a + (2 * w + 1) * 1024);
        } else {
            async16(agp0 + kb, a + w * 1024);
        }
        async16(bgp0 + kb, b + (2 * w) * 1024);
        async16(bgp1 + kb, b + (2 * w + 1) * 1024);
    };

    f32x4 acc[4][NI];
#pragma unroll
    for (int a = 0; a < 4; a++)
#pragma unroll
        for (int b = 0; b < NI; b++) acc[a][b] = (f32x4){0.f, 0.f, 0.f, 0.f};

    const int C = K / 32;
    issue(0, 0);
    for (int c = 0; c < C; c++) {
        __syncthreads();                 // drains chunk c (vmcnt), releases prev-buf readers
        if (c + 1 < C) issue(c + 1, (c + 1) & 1);   // in flight across compute(c)
        const int buf = c & 1;
        bf16x8 af[4], bfr[NI];
#pragma unroll
        for (int mi = 0; mi < 4; mi++)  af[mi]  = *(const bf16x8*)&As[buf][wm + mi * 16 + l16][quad * 8];
#pragma unroll
        for (int ni = 0; ni < NI; ni++) bfr[ni] = *(const bf16x8*)&Bs[buf][wn + ni * 16 + l16][quad * 8];
#pragma unroll
        for (int mi = 0; mi < 4; mi++)
#pragma unroll
            for (int ni = 0; ni < NI; ni++)
                acc[mi][ni] = __builtin_amdgcn_mfma_f32_16x16x32_bf16(af[mi], bfr[ni], acc[mi][ni], 0, 0, 0);
    }

#pragma unroll
    for (int ni = 0; ni < NI; ni++) {
        int cc = n0 + wn + ni * 16 + l16;
        float bvv = bias[cc];
#pragma unroll
        for (int mi = 0; mi < 4; mi++) {
#pragma unroll
            for (int r = 0; r < 4; r++) {
                int m = m0 + wm + mi * 16 + quad * 4 + r;
                if (m >= M) continue;
                float val = acc[mi][ni][r] + bvv;
                if (EPI == 0) {
                    ((unsigned short*)out)[(size_t)m * N + cc] = f2bf(val);
                } else {
                    ((float*)out)[(size_t)m * N + cc] = val;
                }
            }
        }
    }
}

// ---------- sampler: 4 queries/block, wave = 1 query, thread = (h, 4-chan grp) ----------
__global__ __launch_bounds__(256) void msda_sampler_k(
    const float* __restrict__ refpts,            // (BS*NQ, 8) fp32
    const float* __restrict__ oa_buf,            // (BS*NQ, 384) fp32: off[256] | attn[128]
    const unsigned short* __restrict__ v_buf,    // (BS*NV, 256) bf16 row-major
    unsigned short* __restrict__ t_out)          // (BS*NQ, 256) bf16
{
    __shared__ float  oa_s[4][384];
    __shared__ float  ref_s[4][8];
    __shared__ float4 wtab[528];                 // idx = i*33 + ql*8 + h (stride-33 pad)
    __shared__ int4   itab[528];

    const int tid = threadIdx.x;
    const int q0  = blockIdx.x * 4;

    // phase 1: cooperative loads
    {
        const float4* src = (const float4*)(oa_buf + (size_t)q0 * 384);
        float4* dst = (float4*)&oa_s[0][0];
        dst[tid] = src[tid];
        if (tid < 128) dst[256 + tid] = src[256 + tid];
        if (tid < 32) ((float*)ref_s)[tid] = refpts[q0 * 8 + tid];
    }
    __syncthreads();

    // phase 2+3 fused: shuffle softmax (16 lanes = one (q,h) group) + tables
    const int HWs[4]    = {100, 50, 25, 13};
    const int starts[4] = {0, 10000, 12500, 13125};
#pragma unroll
    for (int it = 0; it < 2; it++) {
        int s  = tid + it * 256;                 // 0..511
        int i  = s & 15;                         // l*4+p
        int h  = (s >> 4) & 7;
        int ql = s >> 7;
        int l  = i >> 2, p = i & 3;
        float logit = oa_s[ql][256 + h * 16 + i];
        float m = logit;
#pragma unroll
        for (int off = 1; off < 16; off <<= 1) m = fmaxf(m, __shfl_xor(m, off, 64));
        float e = __expf(logit - m);
        float sum = e;
#pragma unroll
        for (int off = 1; off < 16; off <<= 1) sum += __shfl_xor(sum, off, 64);
        float a = e / sum;

        int Wl = HWs[l];
        float fW = (float)Wl;
        float rx = ref_s[ql][l * 2], ry = ref_s[ql][l * 2 + 1];
        float offx = oa_s[ql][h * 32 + l * 8 + p * 2];
        float offy = oa_s[ql][h * 32 + l * 8 + p * 2 + 1];
        float x = rx * fW + offx - 0.5f;
        float y = ry * fW + offy - 0.5f;
        float xf = floorf(x), yf = floorf(y);
        float fx = x - xf, fy = y - yf;
        int x0 = (int)xf, y0 = (int)yf;
        int x1 = x0 + 1, y1 = y0 + 1;
        float wx0 = (x0 >= 0 && x0 < Wl) ? (1.f - fx) : 0.f;
        float wx1 = (x1 >= 0 && x1 < Wl) ? fx : 0.f;
        float wy0 = (y0 >= 0 && y0 < Wl) ? (1.f - fy) : 0.f;
        float wy1 = (y1 >= 0 && y1 < Wl) ? fy : 0.f;
        int x0c = min(max(x0, 0), Wl - 1), x1c = min(max(x1, 0), Wl - 1);
        int y0c = min(max(y0, 0), Wl - 1), y1c = min(max(y1, 0), Wl - 1);
        int r0 = starts[l] + y0c * Wl, r1 = starts[l] + y1c * Wl;
        int ti = i * 33 + ql * 8 + h;
        wtab[ti] = make_float4(wx0 * wy0 * a, wx1 * wy0 * a, wx0 * wy1 * a, wx1 * wy1 * a);
        itab[ti] = make_int4(r0 + x0c, r0 + x1c, r1 + x0c, r1 + x1c);
    }
    __syncthreads();

    // phase 4: gather + weighted accumulate, 4 channels per thread
    const int dg = tid & 7, h = (tid >> 3) & 7, ql = tid >> 6;
    const int q = q0 + ql;
    const int b = q / NQ;
    const char* base = (const char*)v_buf + (size_t)b * NV * 512;
    const unsigned hd8 = (unsigned)h * 64 + (unsigned)dg * 8;
    const int tbase = ql * 8 + h;

    float a0 = 0.f, a1 = 0.f, a2 = 0.f, a3 = 0.f;
#pragma unroll
    for (int lp = 0; lp < 16; lp++) {
        float4 wv = wtab[lp * 33 + tbase];
        int4   ix = itab[lp * 33 + tbase];
        uint2 s0 = *(const uint2*)(base + (((unsigned)ix.x << 9) + hd8));
        uint2 s1 = *(const uint2*)(base + (((unsigned)ix.y << 9) + hd8));
        uint2 s2 = *(const uint2*)(base + (((unsigned)ix.z << 9) + hd8));
        uint2 s3 = *(const uint2*)(base + (((unsigned)ix.w << 9) + hd8));
        a0 += wv.x * bf2f_lo(s0.x); a1 += wv.x * bf2f_hi(s0.x);
        a2 += wv.x * bf2f_lo(s0.y); a3 += wv.x * bf2f_hi(s0.y);
        a0 += wv.y * bf2f_lo(s1.x); a1 += wv.y * bf2f_hi(s1.x);
        a2 += wv.y * bf2f_lo(s1.y); a3 += wv.y * bf2f_hi(s1.y);
        a0 += wv.z * bf2f_lo(s2.x); a1 += wv.z * bf2f_hi(s2.x);
        a2 += wv.z * bf2f_lo(s2.y); a3 += wv.z * bf2f_hi(s2.y);
        a0 += wv.w * bf2f_lo(s3.x); a1 += wv.w * bf2f_hi(s3.x);
        a2 += wv.w * bf2f_lo(s3.y); a3 += wv.w * bf2f_hi(s3.y);
    }
    unsigned o0 = (unsigned)f2bf(a0) | ((unsigned)f2bf(a1) << 16);
    unsigned o1 = (unsigned)f2bf(a2) | ((unsigned)f2bf(a3) << 16);
    uint2 o = {o0, o1};
    *(uint2*)(t_out + (size_t)q * 256 + h * 32 + dg * 4) = o;
}

extern "C" void kernel_launch(void* const* d_in, const int* in_sizes, int n_in,
                              void* d_out, int out_size, void* d_ws, size_t ws_size,
                              hipStream_t stream) {
    const float* query  = (const float*)d_in[0];
    const float* value  = (const float*)d_in[1];
    const float* refpts = (const float*)d_in[2];
    // d_in[3] = spatial_shapes (int32) — fixed {100,50,25,13}^2, hard-coded.
    const float* W_off  = (const float*)d_in[4];
    const float* b_off  = (const float*)d_in[5];
    const float* W_attn = (const float*)d_in[6];
    const float* b_attn = (const float*)d_in[7];
    const float* W_val  = (const float*)d_in[8];
    const float* b_val  = (const float*)d_in[9];
    const float* W_out  = (const float*)d_in[10];
    const float* b_out  = (const float*)d_in[11];

    char* wsp = (char*)d_ws;
    size_t o = 0;
    auto carve = [&](size_t bytes) -> void* {
        void* p = wsp + o; o += (bytes + 255) & ~(size_t)255; return p;
    };
    unsigned short* Wt_val = (unsigned short*)carve(256 * 256 * 2);
    unsigned short* Wt_out = (unsigned short*)carve(256 * 256 * 2);
    unsigned short* Wt_qa  = (unsigned short*)carve(384 * 256 * 2);
    float*          b_qa   = (float*)carve(384 * 4);
    unsigned short* v_buf  = (unsigned short*)carve((size_t)BS * NV * EMBED * 2);
    // region X: value_bf (27.23 MB), later reused as oa_buf (24.58 MB)
    char* regX = (char*)carve((size_t)BS * NV * EMBED * 2);
    unsigned short* value_bf = (unsigned short*)regX;
    float*          oa_buf   = (float*)regX;
    // region Y: query_bf (8.19 MB), later reused as t_buf (8.19 MB)
    char* regY = (char*)carve((size_t)BS * NQ * EMBED * 2);
    unsigned short* query_bf = (unsigned short*)regY;
    unsigned short* t_buf    = (unsigned short*)regY;

    msda_prep_k<<<18190, 256, 0, stream>>>(value, query, W_val, W_out, W_off, W_attn,
                                           b_off, b_attn, value_bf, query_bf,
                                           Wt_val, Wt_out, Wt_qa, b_qa);

    const int Mv = BS * NV;   // 53176
    const int Mq = BS * NQ;   // 16000
    msda_gemm_k<128, 0><<<dim3((Mv + 127) / 128, 2), 256, 0, stream>>>(value_bf, Wt_val, b_val, v_buf, Mv, 256, 256);
    // qa-GEMM reads query_bf (regY), writes oa_buf (regX) — value_bf consumed.
    msda_gemm_k<64, 1><<<dim3(Mq / 64, 3), 256, 0, stream>>>(query_bf, Wt_qa, b_qa, oa_buf, Mq, 384, 256);
    // sampler reads oa_buf (regX), writes t_buf (regY) — query_bf consumed.
    msda_sampler_k<<<Mq / 4, 256, 0, stream>>>(refpts, oa_buf, v_buf, t_buf);
    msda_gemm_k<64, 1><<<dim3(Mq / 64, 2), 256, 0, stream>>>(t_buf, Wt_out, b_out, (float*)d_out, Mq, 256, 256);
}